// Round 4
// baseline (978.663 us; speedup 1.0000x reference)
//
#include <hip/hip_runtime.h>
#include <stdint.h>

#define MT   30      // top-M candidates
#define KNB  20      // K+1 neighbors
#define DD   512     // descriptor dim
#define XROW 516     // padded LDS row stride (floats)
#define NTILES 120   // upper-triangle 2x2 tiles of 15x15

extern "C" __global__ void __launch_bounds__(512, 4)
mdesc_kernel(const float* __restrict__ X, const float* __restrict__ Q,
             const int* __restrict__ ranks, float* __restrict__ out, int B)
{
    __shared__ alignas(16) float XtS[MT][XROW];
    __shared__ alignas(16) float QS[DD];
    __shared__ double simS[MT][MT + 1];
    __shared__ double simPart[NTILES][4];
    __shared__ double qdotPart[MT][8];
    __shared__ double qdotS[MT];
    __shared__ float  MwS[MT][MT];
    __shared__ double scoreS[MT];
    __shared__ int    orderS[MT];
    __shared__ int    rtS[MT];

    const int b = blockIdx.x;
    const int tid = threadIdx.x;

    if (tid < MT) rtS[tid] = ranks[(size_t)tid * B + b];
    for (int i = tid; i < MT * MT; i += 512) (&MwS[0][0])[i] = 0.0f;
    __syncthreads();

    // ---- gather Xt rows (coalesced float4) + Q ----
    for (int i = tid; i < MT * (DD / 4); i += 512) {
        int row = i >> 7;
        int c = (i & 127) << 2;
        float4 v = *(const float4*)(X + (size_t)rtS[row] * DD + c);
        *(float4*)(&XtS[row][c]) = v;
    }
    if (tid < DD / 4) {
        float4 v = *(const float4*)(Q + (size_t)b * DD + (tid << 2));
        *(float4*)(&QS[tid << 2]) = v;
    }
    __syncthreads();

    // ---- sim = Xt·Xt^T in f64 (BITWISE-IDENTICAL to round 3) ----
    double a00 = 0.0, a01 = 0.0, a10 = 0.0, a11 = 0.0;
    int i0 = 0, i1 = 0, j0 = 0, j1 = 0, tile = 0;
    const bool simActive = (tid < 2 * NTILES);
    const int half = tid & 1;
    if (simActive) {
        tile = tid >> 1;
        int I = 0, rem = tile;
        while (rem >= 15 - I) { rem -= 15 - I; ++I; }
        int J = I + rem;
        i0 = 2 * I; i1 = i0 + 1; j0 = 2 * J; j1 = j0 + 1;
        const int dbase = half * 256;
        for (int d = dbase; d < dbase + 256; d += 4) {
            float4 va0 = *(const float4*)&XtS[i0][d];
            float4 va1 = *(const float4*)&XtS[i1][d];
            float4 vb0 = *(const float4*)&XtS[j0][d];
            float4 vb1 = *(const float4*)&XtS[j1][d];
            const float* A0 = (const float*)&va0;
            const float* A1 = (const float*)&va1;
            const float* B0 = (const float*)&vb0;
            const float* B1 = (const float*)&vb1;
            #pragma unroll
            for (int c = 0; c < 4; ++c) {
                double x0 = (double)A0[c], x1 = (double)A1[c];
                double y0 = (double)B0[c], y1 = (double)B1[c];
                a00 = fma(x0, y0, a00);
                a01 = fma(x0, y1, a01);
                a10 = fma(x1, y0, a10);
                a11 = fma(x1, y1, a11);
            }
        }
        if (half) {
            simPart[tile][0] = a00; simPart[tile][1] = a01;
            simPart[tile][2] = a10; simPart[tile][3] = a11;
        }
    }
    __syncthreads();
    if (simActive && half == 0) {
        a00 += simPart[tile][0]; a01 += simPart[tile][1];
        a10 += simPart[tile][2]; a11 += simPart[tile][3];
        simS[i0][j0] = a00; simS[j0][i0] = a00;
        simS[i0][j1] = a01; simS[j1][i0] = a01;
        simS[i1][j0] = a10; simS[j0][i1] = a10;
        simS[i1][j1] = a11; simS[j1][i1] = a11;
    }
    // ---- qdots (BITWISE-IDENTICAL to round 3) ----
    if (tid < 240) {
        int m = tid >> 3, s = tid & 7;
        double acc = 0.0;
        const int dbase = s * 64;
        for (int d = dbase; d < dbase + 64; d += 4) {
            float4 q = *(const float4*)&QS[d];
            float4 x = *(const float4*)&XtS[m][d];
            const float* qq = (const float*)&q;
            const float* xx = (const float*)&x;
            #pragma unroll
            for (int c = 0; c < 4; ++c)
                acc = fma((double)qq[c], (double)xx[c], acc);
        }
        qdotPart[m][s] = acc;
    }
    __syncthreads();
    if (tid < MT) {
        double acc = 0.0;
        #pragma unroll
        for (int s = 0; s < 8; ++s) acc += qdotPart[tid][s];
        qdotS[tid] = acc;
    }
    __syncthreads();

    // ---- top-20 selection: register-resident row, IDENTICAL semantics ----
    if (tid < MT) {
        const int m = tid;
        double v[MT];
        #pragma unroll
        for (int j = 0; j < MT; ++j) v[j] = simS[m][j];
        unsigned used = 0;
        double Wsum = 0.0, sAcc = 0.0;
        for (int k = 0; k < KNB; ++k) {
            double best = -1.0e300; int bj = 0;
            #pragma unroll
            for (int j = 0; j < MT; ++j) {
                if (!(used & (1u << j)) && v[j] > best) { best = v[j]; bj = j; }
            }
            used |= (1u << bj);
            double w = (k == 0) ? 1.0 : best * 0.15;
            Wsum += w;
            sAcc = fma(w, qdotS[bj], sAcc);
            MwS[m][bj] = (float)w;
        }
        scoreS[m] = sAcc / Wsum;
        float inv = (float)(1.0 / Wsum);
        #pragma unroll
        for (int j = 0; j < MT; ++j)
            if (used & (1u << j)) MwS[m][j] *= inv;
    }
    __syncthreads();

    // ---- stable rank of scores (desc, ties -> lowest index) ----
    if (tid < MT) {
        double mysc = scoreS[tid];
        int pos = 0;
        for (int j = 0; j < MT; ++j) {
            double v = scoreS[j];
            if (v > mysc || (v == mysc && j < tid)) ++pos;
        }
        orderS[pos] = tid;
    }
    __syncthreads();

    const size_t sec = (size_t)B * MT;
    if (tid < MT) {
        int r = tid;
        int src = orderS[r];
        out[(size_t)b * MT + r]            = (float)rtS[src];
        out[sec + (size_t)b * MT + tid]    = (float)scoreS[tid];
        out[2 * sec + (size_t)b * MT + r]  = (float)src;
    }

    // ---- x_dba: wave = (col-half, 8-row group), register accumulators ----
    {
        const int w   = tid >> 6;        // 0..7
        const int g   = w >> 1;          // row group 0..3
        const int h   = w & 1;           // column half
        const int lane = tid & 63;
        const int c   = h * 256 + lane * 4;
        const int r0  = g * 8;
        const int nr  = (g == 3) ? 6 : 8;
        float4 acc[8];
        #pragma unroll
        for (int r = 0; r < 8; ++r) acc[r] = make_float4(0.f, 0.f, 0.f, 0.f);
        for (int j = 0; j < MT; ++j) {
            float4 xv = *(const float4*)&XtS[j][c];
            #pragma unroll
            for (int r = 0; r < 8; ++r) {
                if (r < nr) {
                    float wj = MwS[r0 + r][j];
                    acc[r].x = fmaf(wj, xv.x, acc[r].x);
                    acc[r].y = fmaf(wj, xv.y, acc[r].y);
                    acc[r].z = fmaf(wj, xv.z, acc[r].z);
                    acc[r].w = fmaf(wj, xv.w, acc[r].w);
                }
            }
        }
        const size_t xbase = 3 * sec;
        #pragma unroll
        for (int r = 0; r < 8; ++r) {
            if (r < nr) {
                *(float4*)(out + xbase + ((size_t)b * MT + (r0 + r)) * DD + c) = acc[r];
            }
        }
    }
}

extern "C" void kernel_launch(void* const* d_in, const int* in_sizes, int n_in,
                              void* d_out, int out_size, void* d_ws, size_t ws_size,
                              hipStream_t stream)
{
    const float* X = (const float*)d_in[0];
    const float* Q = (const float*)d_in[1];
    const int* ranks = (const int*)d_in[2];
    const int B = in_sizes[1] / DD;   // 4096
    mdesc_kernel<<<dim3(B), dim3(512), 0, stream>>>(X, Q, ranks, (float*)d_out, B);
}

// Round 5
// 953.515 us; speedup vs baseline: 1.0264x; 1.0264x over previous
//
#include <hip/hip_runtime.h>
#include <stdint.h>

#define MT   30      // top-M candidates
#define KNB  20      // K+1 neighbors
#define DD   512     // descriptor dim
#define XROW 516     // padded LDS row stride (floats)
#define NTILES 120   // upper-triangle 2x2 tiles of 15x15

extern "C" __global__ void __launch_bounds__(512)
mdesc_kernel(const float* __restrict__ X, const float* __restrict__ Q,
             const int* __restrict__ ranks, float* __restrict__ out, int B)
{
    __shared__ alignas(16) float XtS[MT][XROW];
    __shared__ alignas(16) float QS[DD];
    __shared__ double simS[MT][MT + 1];
    __shared__ double qdotPart[MT][8];
    __shared__ double qdotS[MT];
    __shared__ float  MwS[MT][MT];
    __shared__ double scoreS[MT];
    __shared__ int    orderS[MT];
    __shared__ int    rtS[MT];

    const int b = blockIdx.x;
    const int tid = threadIdx.x;

    if (tid < MT) rtS[tid] = ranks[(size_t)tid * B + b];

    // ---- gather Xt rows (coalesced float4) + Q; row ids read straight from global ----
    for (int i = tid; i < MT * (DD / 4); i += 512) {
        int row = i >> 7;
        int c = (i & 127) << 2;
        int rid = ranks[(size_t)row * B + b];
        float4 v = *(const float4*)(X + (size_t)rid * DD + c);
        *(float4*)(&XtS[row][c]) = v;
    }
    if (tid < DD / 4) {
        float4 v = *(const float4*)(Q + (size_t)b * DD + (tid << 2));
        *(float4*)(&QS[tid << 2]) = v;
    }
    __syncthreads();

    // ---- sim = Xt·Xt^T in f64 (BITWISE-IDENTICAL chains; halves combined via shfl) ----
    {
        double a00 = 0.0, a01 = 0.0, a10 = 0.0, a11 = 0.0;
        int i0 = 0, i1 = 0, j0 = 0, j1 = 0;
        const bool simActive = (tid < 2 * NTILES);
        const int half = tid & 1;
        if (simActive) {
            int tile = tid >> 1;
            int I = 0, rem = tile;
            while (rem >= 15 - I) { rem -= 15 - I; ++I; }
            int J = I + rem;
            i0 = 2 * I; i1 = i0 + 1; j0 = 2 * J; j1 = j0 + 1;
            const int dbase = half * 256;
            for (int d = dbase; d < dbase + 256; d += 4) {
                float4 va0 = *(const float4*)&XtS[i0][d];
                float4 va1 = *(const float4*)&XtS[i1][d];
                float4 vb0 = *(const float4*)&XtS[j0][d];
                float4 vb1 = *(const float4*)&XtS[j1][d];
                const float* A0 = (const float*)&va0;
                const float* A1 = (const float*)&va1;
                const float* B0 = (const float*)&vb0;
                const float* B1 = (const float*)&vb1;
                #pragma unroll
                for (int c = 0; c < 4; ++c) {
                    double x0 = (double)A0[c], x1 = (double)A1[c];
                    double y0 = (double)B0[c], y1 = (double)B1[c];
                    a00 = fma(x0, y0, a00);
                    a01 = fma(x0, y1, a01);
                    a10 = fma(x1, y0, a10);
                    a11 = fma(x1, y1, a11);
                }
            }
        }
        // pairs (2k, 2k+1) never cross a wave boundary
        double p00 = __shfl_xor(a00, 1);
        double p01 = __shfl_xor(a01, 1);
        double p10 = __shfl_xor(a10, 1);
        double p11 = __shfl_xor(a11, 1);
        if (simActive && half == 0) {
            a00 += p00; a01 += p01;   // half0 + half1: same operands, same order as before
            a10 += p10; a11 += p11;
            simS[i0][j0] = a00; simS[j0][i0] = a00;
            simS[i0][j1] = a01; simS[j1][i0] = a01;
            simS[i1][j0] = a10; simS[j0][i1] = a10;
            simS[i1][j1] = a11; simS[j1][i1] = a11;
        }
    }
    // ---- qdot partials (BITWISE-IDENTICAL) ----
    if (tid < 240) {
        int m = tid >> 3, s = tid & 7;
        double acc = 0.0;
        const int dbase = s * 64;
        for (int d = dbase; d < dbase + 64; d += 4) {
            float4 q = *(const float4*)&QS[d];
            float4 x = *(const float4*)&XtS[m][d];
            const float* qq = (const float*)&q;
            const float* xx = (const float*)&x;
            #pragma unroll
            for (int c = 0; c < 4; ++c)
                acc = fma((double)qq[c], (double)xx[c], acc);
        }
        qdotPart[m][s] = acc;
    }
    __syncthreads();

    // ---- wave-0 serial section: qdot final, selection, score, rank, head outputs ----
    const size_t sec = (size_t)B * MT;
    if (tid < MT) {
        {
            double acc = 0.0;
            #pragma unroll
            for (int s = 0; s < 8; ++s) acc += qdotPart[tid][s];
            qdotS[tid] = acc;
        }
        // top-20 selection (desc value, ties -> lowest index) — verbatim round 3
        const int m = tid;
        unsigned used = 0;
        double Wsum = 0.0, sAcc = 0.0;
        for (int k = 0; k < KNB; ++k) {
            double best = -1.0e300; int bj = 0;
            for (int j = 0; j < MT; ++j) {
                if (used & (1u << j)) continue;
                double v = simS[m][j];
                if (v > best) { best = v; bj = j; }
            }
            used |= (1u << bj);
            double w = (k == 0) ? 1.0 : best * 0.15;
            Wsum += w;
            sAcc = fma(w, qdotS[bj], sAcc);
            MwS[m][bj] = (float)w;
        }
        scoreS[m] = sAcc / Wsum;
        float inv = (float)(1.0 / Wsum);
        for (int j = 0; j < MT; ++j) {
            if (used & (1u << j)) MwS[m][j] *= inv;
            else                  MwS[m][j] = 0.0f;
        }
        // stable rank (desc, ties -> lowest index) — verbatim
        double mysc = scoreS[tid];
        int pos = 0;
        for (int j = 0; j < MT; ++j) {
            double v = scoreS[j];
            if (v > mysc || (v == mysc && j < tid)) ++pos;
        }
        orderS[pos] = tid;
        // head outputs
        int r = tid;
        int src = orderS[r];
        out[(size_t)b * MT + r]            = (float)rtS[src];
        out[sec + (size_t)b * MT + tid]    = (float)scoreS[tid];
        out[2 * sec + (size_t)b * MT + r]  = (float)src;
    }
    __syncthreads();

    // ---- x_dba: 8 waves = (row-group g, col-half h), register accumulators ----
    {
        const int w    = tid >> 6;       // 0..7
        const int g    = w >> 1;         // row group 0..3
        const int h    = w & 1;          // column half
        const int lane = tid & 63;
        const int c    = h * 256 + lane * 4;
        const int r0   = g * 8;
        const int nr   = (g == 3) ? 6 : 8;
        float4 acc[8];
        #pragma unroll
        for (int r = 0; r < 8; ++r) acc[r] = make_float4(0.f, 0.f, 0.f, 0.f);
        for (int j = 0; j < MT; ++j) {
            float4 xv = *(const float4*)&XtS[j][c];
            #pragma unroll
            for (int r = 0; r < 8; ++r) {
                if (r < nr) {
                    float wj = MwS[r0 + r][j];
                    acc[r].x = fmaf(wj, xv.x, acc[r].x);
                    acc[r].y = fmaf(wj, xv.y, acc[r].y);
                    acc[r].z = fmaf(wj, xv.z, acc[r].z);
                    acc[r].w = fmaf(wj, xv.w, acc[r].w);
                }
            }
        }
        const size_t xbase = 3 * sec;
        #pragma unroll
        for (int r = 0; r < 8; ++r) {
            if (r < nr) {
                *(float4*)(out + xbase + ((size_t)b * MT + (r0 + r)) * DD + c) = acc[r];
            }
        }
    }
}

extern "C" void kernel_launch(void* const* d_in, const int* in_sizes, int n_in,
                              void* d_out, int out_size, void* d_ws, size_t ws_size,
                              hipStream_t stream)
{
    const float* X = (const float*)d_in[0];
    const float* Q = (const float*)d_in[1];
    const int* ranks = (const int*)d_in[2];
    const int B = in_sizes[1] / DD;   // 4096
    mdesc_kernel<<<dim3(B), dim3(512), 0, stream>>>(X, Q, ranks, (float*)d_out, B);
}

// Round 6
// 885.530 us; speedup vs baseline: 1.1052x; 1.0768x over previous
//
#include <hip/hip_runtime.h>
#include <stdint.h>

#define MT   30      // top-M candidates
#define KNB  20      // K+1 neighbors
#define DD   512     // descriptor dim
#define XROW 516     // padded LDS row stride (floats), 16B-aligned rows
#define NTILES 120   // upper-triangle 2x2 tiles of 15x15

// 16B-chunk swizzle within each row: permutation of chunks 0..127.
// bank/4 of (row, k) becomes (5*row + (row>>1) + k) mod 8 -> for sim's
// even-row lanes this is (3*I + k) mod 8, injective in I (3 coprime 8).
#define SWZ(row, k) ((((k) + 4 * (row) + ((row) >> 1)) & 127) << 2)
#define CH(row, k) (*(float4*)&XtS[row][SWZ(row, k)])

extern "C" __global__ void __launch_bounds__(256)
mdesc_kernel(const float* __restrict__ X, const float* __restrict__ Q,
             const int* __restrict__ ranks, float* __restrict__ out, int B)
{
    __shared__ alignas(16) float XtS[MT][XROW];
    __shared__ alignas(16) float QS[DD];
    __shared__ double simS[MT][MT + 1];
    __shared__ double simPart[NTILES][4];
    __shared__ double qdotPart[MT][8];
    __shared__ double qdotS[MT];
    __shared__ float  MwS[MT][MT];
    __shared__ double scoreS[MT];
    __shared__ int    orderS[MT];
    __shared__ int    rtS[MT];

    const int b = blockIdx.x;
    const int tid = threadIdx.x;

    if (tid < MT) rtS[tid] = ranks[(size_t)tid * B + b];
    for (int i = tid; i < MT * MT; i += 256) (&MwS[0][0])[i] = 0.0f;
    __syncthreads();

    // ---- gather Xt rows (coalesced float4) + Q; swizzled LDS placement ----
    for (int i = tid; i < MT * (DD / 4); i += 256) {
        int row = i >> 7;
        int k = i & 127;
        float4 v = *(const float4*)(X + (size_t)rtS[row] * DD + (k << 2));
        CH(row, k) = v;
    }
    if (tid < DD / 4) {
        float4 v = *(const float4*)(Q + (size_t)b * DD + (tid << 2));
        *(float4*)(&QS[tid << 2]) = v;
    }
    __syncthreads();

    // ---- sim = Xt·Xt^T in f64 (BITWISE-IDENTICAL chains to round 3) ----
    double a00 = 0.0, a01 = 0.0, a10 = 0.0, a11 = 0.0;
    int i0 = 0, i1 = 0, j0 = 0, j1 = 0, tile = 0;
    const bool simActive = (tid < 2 * NTILES);
    const int half = tid & 1;
    if (simActive) {
        tile = tid >> 1;
        int I = 0, rem = tile;
        while (rem >= 15 - I) { rem -= 15 - I; ++I; }
        int J = I + rem;
        i0 = 2 * I; i1 = i0 + 1; j0 = 2 * J; j1 = j0 + 1;
        const int kbase = half * 64;
        for (int k = kbase; k < kbase + 64; ++k) {
            float4 va0 = CH(i0, k);
            float4 va1 = CH(i1, k);
            float4 vb0 = CH(j0, k);
            float4 vb1 = CH(j1, k);
            const float* A0 = (const float*)&va0;
            const float* A1 = (const float*)&va1;
            const float* B0 = (const float*)&vb0;
            const float* B1 = (const float*)&vb1;
            #pragma unroll
            for (int c = 0; c < 4; ++c) {
                double x0 = (double)A0[c], x1 = (double)A1[c];
                double y0 = (double)B0[c], y1 = (double)B1[c];
                a00 = fma(x0, y0, a00);
                a01 = fma(x0, y1, a01);
                a10 = fma(x1, y0, a10);
                a11 = fma(x1, y1, a11);
            }
        }
        if (half) {
            simPart[tile][0] = a00; simPart[tile][1] = a01;
            simPart[tile][2] = a10; simPart[tile][3] = a11;
        }
    }
    __syncthreads();
    if (simActive && half == 0) {
        a00 += simPart[tile][0]; a01 += simPart[tile][1];
        a10 += simPart[tile][2]; a11 += simPart[tile][3];
        simS[i0][j0] = a00; simS[j0][i0] = a00;
        simS[i0][j1] = a01; simS[j1][i0] = a01;
        simS[i1][j0] = a10; simS[j0][i1] = a10;
        simS[i1][j1] = a11; simS[j1][i1] = a11;
    }
    // ---- qdots = Q·Xt[m] in f64 (BITWISE-IDENTICAL) ----
    if (tid < 240) {
        int m = tid >> 3, s = tid & 7;
        double acc = 0.0;
        const int kb = s * 16;
        for (int k = kb; k < kb + 16; ++k) {
            float4 q = *(const float4*)&QS[k << 2];
            float4 x = CH(m, k);
            const float* qq = (const float*)&q;
            const float* xx = (const float*)&x;
            #pragma unroll
            for (int c = 0; c < 4; ++c)
                acc = fma((double)qq[c], (double)xx[c], acc);
        }
        qdotPart[m][s] = acc;
    }
    __syncthreads();
    if (tid < MT) {
        double acc = 0.0;
        #pragma unroll
        for (int s = 0; s < 8; ++s) acc += qdotPart[tid][s];
        qdotS[tid] = acc;
    }
    __syncthreads();

    // ---- per-row top-20 selection (verbatim round 3) ----
    if (tid < MT) {
        const int m = tid;
        unsigned used = 0;
        double Wsum = 0.0, sAcc = 0.0;
        for (int k = 0; k < KNB; ++k) {
            double best = -1.0e300; int bj = 0;
            for (int j = 0; j < MT; ++j) {
                if (used & (1u << j)) continue;
                double v = simS[m][j];
                if (v > best) { best = v; bj = j; }
            }
            used |= (1u << bj);
            double w = (k == 0) ? 1.0 : best * 0.15;
            Wsum += w;
            sAcc = fma(w, qdotS[bj], sAcc);
            MwS[m][bj] = (float)w;
        }
        scoreS[m] = sAcc / Wsum;
        float inv = (float)(1.0 / Wsum);
        for (int j = 0; j < MT; ++j)
            if (used & (1u << j)) MwS[m][j] *= inv;
    }
    __syncthreads();

    // ---- stable rank of scores (verbatim round 3) ----
    if (tid < MT) {
        double mysc = scoreS[tid];
        int pos = 0;
        for (int j = 0; j < MT; ++j) {
            double v = scoreS[j];
            if (v > mysc || (v == mysc && j < tid)) ++pos;
        }
        orderS[pos] = tid;
    }
    __syncthreads();

    const size_t sec = (size_t)B * MT;
    if (tid < MT) {
        int r = tid;
        int src = orderS[r];
        out[(size_t)b * MT + r]            = (float)rtS[src];
        out[sec + (size_t)b * MT + tid]    = (float)scoreS[tid];
        out[2 * sec + (size_t)b * MT + r]  = (float)src;
    }
    __syncthreads();

    // ---- x_dba: 4 waves = row groups, 2 col-half passes, register acc ----
    {
        const int w    = tid >> 6;       // 0..3 (row group)
        const int lane = tid & 63;
        const int r0   = w * 8;
        const int nr   = (w == 3) ? 6 : 8;
        const size_t xbase = 3 * sec;
        #pragma unroll
        for (int h = 0; h < 2; ++h) {
            const int kk = h * 64 + lane;         // chunk index 0..127
            float4 acc[8];
            #pragma unroll
            for (int r = 0; r < 8; ++r) acc[r] = make_float4(0.f, 0.f, 0.f, 0.f);
            for (int j = 0; j < MT; ++j) {
                float4 xv = CH(j, kk);
                #pragma unroll
                for (int r = 0; r < 8; ++r) {
                    if (r < nr) {
                        float wj = MwS[r0 + r][j];
                        acc[r].x = fmaf(wj, xv.x, acc[r].x);
                        acc[r].y = fmaf(wj, xv.y, acc[r].y);
                        acc[r].z = fmaf(wj, xv.z, acc[r].z);
                        acc[r].w = fmaf(wj, xv.w, acc[r].w);
                    }
                }
            }
            #pragma unroll
            for (int r = 0; r < 8; ++r) {
                if (r < nr) {
                    *(float4*)(out + xbase + ((size_t)b * MT + (r0 + r)) * DD + (kk << 2)) = acc[r];
                }
            }
        }
    }
}

extern "C" void kernel_launch(void* const* d_in, const int* in_sizes, int n_in,
                              void* d_out, int out_size, void* d_ws, size_t ws_size,
                              hipStream_t stream)
{
    const float* X = (const float*)d_in[0];
    const float* Q = (const float*)d_in[1];
    const int* ranks = (const int*)d_in[2];
    const int B = in_sizes[1] / DD;   // 4096
    mdesc_kernel<<<dim3(B), dim3(256), 0, stream>>>(X, Q, ranks, (float*)d_out, B);
}

// Round 7
// 474.735 us; speedup vs baseline: 2.0615x; 1.8653x over previous
//
#include <hip/hip_runtime.h>
#include <stdint.h>

#define MT   30      // top-M candidates
#define KNB  20      // K+1 neighbors
#define DD   512     // descriptor dim
#define XROW 516     // padded LDS row stride (floats)
#define NTILES 120   // upper-triangle 2x2 tiles of 15x15
#define WSTRIDE 960  // per-query float stride of weight matrix in ws

// ================= Kernel A: decisions (round-3 verbatim phases) =================
extern "C" __global__ void __launch_bounds__(256)
mdesc_decide(const float* __restrict__ X, const float* __restrict__ Q,
             const int* __restrict__ ranks, float* __restrict__ out,
             float* __restrict__ wsF, int B)
{
    __shared__ alignas(16) float XtS[MT][XROW];
    __shared__ alignas(16) float QS[DD];
    __shared__ double simS[MT][MT + 1];
    __shared__ double simPart[NTILES][4];
    __shared__ double qdotPart[MT][8];
    __shared__ double qdotS[MT];
    __shared__ float  MwS[MT][MT];
    __shared__ double scoreS[MT];
    __shared__ int    orderS[MT];
    __shared__ int    rtS[MT];

    const int b = blockIdx.x;
    const int tid = threadIdx.x;

    if (tid < MT) rtS[tid] = ranks[(size_t)tid * B + b];
    for (int i = tid; i < MT * MT; i += 256) (&MwS[0][0])[i] = 0.0f;
    __syncthreads();

    // ---- gather Xt rows (coalesced float4) + Q ----
    for (int i = tid; i < MT * (DD / 4); i += 256) {
        int row = i >> 7;
        int c = (i & 127) << 2;
        float4 v = *(const float4*)(X + (size_t)rtS[row] * DD + c);
        *(float4*)(&XtS[row][c]) = v;
    }
    if (tid < DD / 4) {
        float4 v = *(const float4*)(Q + (size_t)b * DD + (tid << 2));
        *(float4*)(&QS[tid << 2]) = v;
    }
    __syncthreads();

    // ---- sim = Xt·Xt^T in f64 (BITWISE-IDENTICAL to round 3) ----
    double a00 = 0.0, a01 = 0.0, a10 = 0.0, a11 = 0.0;
    int i0 = 0, i1 = 0, j0 = 0, j1 = 0, tile = 0;
    const bool simActive = (tid < 2 * NTILES);
    const int half = tid & 1;
    if (simActive) {
        tile = tid >> 1;
        int I = 0, rem = tile;
        while (rem >= 15 - I) { rem -= 15 - I; ++I; }
        int J = I + rem;
        i0 = 2 * I; i1 = i0 + 1; j0 = 2 * J; j1 = j0 + 1;
        const int dbase = half * 256;
        for (int d = dbase; d < dbase + 256; d += 4) {
            float4 va0 = *(const float4*)&XtS[i0][d];
            float4 va1 = *(const float4*)&XtS[i1][d];
            float4 vb0 = *(const float4*)&XtS[j0][d];
            float4 vb1 = *(const float4*)&XtS[j1][d];
            const float* A0 = (const float*)&va0;
            const float* A1 = (const float*)&va1;
            const float* B0 = (const float*)&vb0;
            const float* B1 = (const float*)&vb1;
            #pragma unroll
            for (int c = 0; c < 4; ++c) {
                double x0 = (double)A0[c], x1 = (double)A1[c];
                double y0 = (double)B0[c], y1 = (double)B1[c];
                a00 = fma(x0, y0, a00);
                a01 = fma(x0, y1, a01);
                a10 = fma(x1, y0, a10);
                a11 = fma(x1, y1, a11);
            }
        }
        if (half) {
            simPart[tile][0] = a00; simPart[tile][1] = a01;
            simPart[tile][2] = a10; simPart[tile][3] = a11;
        }
    }
    __syncthreads();
    if (simActive && half == 0) {
        a00 += simPart[tile][0]; a01 += simPart[tile][1];
        a10 += simPart[tile][2]; a11 += simPart[tile][3];
        simS[i0][j0] = a00; simS[j0][i0] = a00;
        simS[i0][j1] = a01; simS[j1][i0] = a01;
        simS[i1][j0] = a10; simS[j0][i1] = a10;
        simS[i1][j1] = a11; simS[j1][i1] = a11;
    }
    // ---- qdots = Q·Xt[m] in f64 (8 lanes per row) ----
    if (tid < 240) {
        int m = tid >> 3, s = tid & 7;
        double acc = 0.0;
        const int dbase = s * 64;
        for (int d = dbase; d < dbase + 64; d += 4) {
            float4 q = *(const float4*)&QS[d];
            float4 x = *(const float4*)&XtS[m][d];
            const float* qq = (const float*)&q;
            const float* xx = (const float*)&x;
            #pragma unroll
            for (int c = 0; c < 4; ++c)
                acc = fma((double)qq[c], (double)xx[c], acc);
        }
        qdotPart[m][s] = acc;
    }
    __syncthreads();
    if (tid < MT) {
        double acc = 0.0;
        #pragma unroll
        for (int s = 0; s < 8; ++s) acc += qdotPart[tid][s];
        qdotS[tid] = acc;
    }
    __syncthreads();

    // ---- per-row top-20 selection (verbatim round 3) ----
    if (tid < MT) {
        const int m = tid;
        unsigned used = 0;
        double Wsum = 0.0, sAcc = 0.0;
        for (int k = 0; k < KNB; ++k) {
            double best = -1.0e300; int bj = 0;
            for (int j = 0; j < MT; ++j) {
                if (used & (1u << j)) continue;
                double v = simS[m][j];
                if (v > best) { best = v; bj = j; }
            }
            used |= (1u << bj);
            double w = (k == 0) ? 1.0 : best * 0.15;
            Wsum += w;
            sAcc = fma(w, qdotS[bj], sAcc);
            MwS[m][bj] = (float)w;
        }
        scoreS[m] = sAcc / Wsum;
        float inv = (float)(1.0 / Wsum);
        for (int j = 0; j < MT; ++j)
            if (used & (1u << j)) MwS[m][j] *= inv;
    }
    __syncthreads();

    // ---- stable rank of scores (verbatim round 3) ----
    if (tid < MT) {
        double mysc = scoreS[tid];
        int pos = 0;
        for (int j = 0; j < MT; ++j) {
            double v = scoreS[j];
            if (v > mysc || (v == mysc && j < tid)) ++pos;
        }
        orderS[pos] = tid;
    }
    __syncthreads();

    const size_t sec = (size_t)B * MT;
    if (tid < MT) {
        int r = tid;
        int src = orderS[r];
        out[(size_t)b * MT + r]            = (float)rtS[src];
        out[sec + (size_t)b * MT + tid]    = (float)scoreS[tid];
        out[2 * sec + (size_t)b * MT + r]  = (float)src;
    }

    // ---- export normalized weight matrix to workspace ----
    for (int i = tid; i < MT * MT; i += 256)
        wsF[(size_t)b * WSTRIDE + i] = (&MwS[0][0])[i];
}

// ================= Kernel B: x_dba = w(30x30) * gathered-X(30x512) =================
extern "C" __global__ void __launch_bounds__(256)
mdesc_xdba(const float* __restrict__ X, const int* __restrict__ ranks,
           const float* __restrict__ wsF, float* __restrict__ out, int B)
{
    __shared__ float wS[MT][MT];
    __shared__ int   rtS[MT];

    const int b = blockIdx.x;
    const int tid = threadIdx.x;

    if (tid < MT) rtS[tid] = ranks[(size_t)tid * B + b];
    for (int i = tid; i < MT * MT; i += 256)
        (&wS[0][0])[i] = wsF[(size_t)b * WSTRIDE + i];
    __syncthreads();

    const int c  = tid & 127;          // float4 chunk 0..127
    const int g  = tid >> 7;           // row group 0 or 1 (15 rows each)
    const int r0 = g * 15;

    float4 acc[15];
    #pragma unroll
    for (int r = 0; r < 15; ++r) acc[r] = make_float4(0.f, 0.f, 0.f, 0.f);

    for (int j = 0; j < MT; ++j) {
        float4 xv = *(const float4*)(X + (size_t)rtS[j] * DD + (c << 2));
        #pragma unroll
        for (int r = 0; r < 15; ++r) {
            float wj = wS[r0 + r][j];
            acc[r].x = fmaf(wj, xv.x, acc[r].x);
            acc[r].y = fmaf(wj, xv.y, acc[r].y);
            acc[r].z = fmaf(wj, xv.z, acc[r].z);
            acc[r].w = fmaf(wj, xv.w, acc[r].w);
        }
    }

    const size_t xbase = 3 * (size_t)B * MT;
    #pragma unroll
    for (int r = 0; r < 15; ++r) {
        *(float4*)(out + xbase + ((size_t)b * MT + (r0 + r)) * DD + (c << 2)) = acc[r];
    }
}

extern "C" void kernel_launch(void* const* d_in, const int* in_sizes, int n_in,
                              void* d_out, int out_size, void* d_ws, size_t ws_size,
                              hipStream_t stream)
{
    const float* X = (const float*)d_in[0];
    const float* Q = (const float*)d_in[1];
    const int* ranks = (const int*)d_in[2];
    const int B = in_sizes[1] / DD;   // 4096
    float* wsF = (float*)d_ws;        // B*960 floats = 14.7 MB
    mdesc_decide<<<dim3(B), dim3(256), 0, stream>>>(X, Q, ranks, (float*)d_out, wsF, B);
    mdesc_xdba<<<dim3(B), dim3(256), 0, stream>>>(X, ranks, wsF, (float*)d_out, B);
}

// Round 8
// 385.119 us; speedup vs baseline: 2.5412x; 1.2327x over previous
//
#include <hip/hip_runtime.h>
#include <stdint.h>

#define MT   30      // top-M candidates
#define KNB  20      // K+1 neighbors
#define DD   512     // descriptor dim
#define HROW 268     // padded half-row stride (floats), 16B-aligned, odd*4 mod 32 spread
#define WSTRIDE 960  // per-query float stride of weight matrix in ws

// physical row permutation: even logical rows -> 0..14, odd -> 15..29
#define PR(r) ((((r) & 1) * 15) + ((r) >> 1))

// ===== Kernel A: decisions. Round-3 arithmetic chains verbatim; d-half staged. =====
extern "C" __global__ void __launch_bounds__(256)
mdesc_decide(const float* __restrict__ X, const float* __restrict__ Q,
             const int* __restrict__ ranks, float* __restrict__ out,
             float* __restrict__ wsF, int B)
{
    __shared__ alignas(16) float XtS[MT][HROW];   // one d-half, physically permuted rows
    __shared__ alignas(16) float QS[DD];
    __shared__ double simS[MT][MT + 1];
    __shared__ double qdotPart[MT][8];
    __shared__ double qdotS[MT];
    __shared__ float  MwS[MT][MT];
    __shared__ double scoreS[MT];
    __shared__ int    orderS[MT];
    __shared__ int    rtS[MT];

    const int b = blockIdx.x;
    const int tid = threadIdx.x;

    if (tid < MT) rtS[tid] = ranks[(size_t)tid * B + b];
    for (int i = tid; i < MT * MT; i += 256) (&MwS[0][0])[i] = 0.0f;
    __syncthreads();

    // roles: waves 0-1 = sim tiles (120 lanes), waves 2-3 = qdot (120 lanes)
    const bool isSim  = (tid < 120);
    const bool isQdot = (tid >= 128 && tid < 248);
    int i0 = 0, i1 = 0, j0 = 0, j1 = 0;
    if (isSim) {
        int I = 0, rem = tid;
        while (rem >= 15 - I) { rem -= 15 - I; ++I; }
        int J = I + rem;
        i0 = 2 * I; i1 = i0 + 1; j0 = 2 * J; j1 = j0 + 1;
    }
    const int qm = (tid - 128) >> 2;   // 0..29
    const int qs = (tid - 128) & 3;    // 0..3

    double h00 = 0.0, h01 = 0.0, h10 = 0.0, h11 = 0.0;  // saved half-0 sim accums

    for (int half = 0; half < 2; ++half) {
        // ---- stage this d-half of Xt (coalesced float4), + Q on half 0 ----
        for (int i = tid; i < MT * 64; i += 256) {
            int row = i >> 6;
            int k = i & 63;
            float4 v = *(const float4*)(X + (size_t)rtS[row] * DD + half * 256 + (k << 2));
            *(float4*)(&XtS[PR(row)][k << 2]) = v;
        }
        if (half == 0 && tid < 128) {
            float4 v = *(const float4*)(Q + (size_t)b * DD + (tid << 2));
            *(float4*)(&QS[tid << 2]) = v;
        }
        __syncthreads();

        // ---- sim: per-tile 2x2 accums, chain = ascending d within this half ----
        if (isSim) {
            double a00 = 0.0, a01 = 0.0, a10 = 0.0, a11 = 0.0;
            const float* R0 = &XtS[PR(i0)][0];
            const float* R1 = &XtS[PR(i1)][0];
            const float* C0 = &XtS[PR(j0)][0];
            const float* C1 = &XtS[PR(j1)][0];
            for (int k = 0; k < 64; ++k) {
                float4 va0 = *(const float4*)(R0 + (k << 2));
                float4 va1 = *(const float4*)(R1 + (k << 2));
                float4 vb0 = *(const float4*)(C0 + (k << 2));
                float4 vb1 = *(const float4*)(C1 + (k << 2));
                const float* A0 = (const float*)&va0;
                const float* A1 = (const float*)&va1;
                const float* B0 = (const float*)&vb0;
                const float* B1 = (const float*)&vb1;
                #pragma unroll
                for (int c = 0; c < 4; ++c) {
                    double x0 = (double)A0[c], x1 = (double)A1[c];
                    double y0 = (double)B0[c], y1 = (double)B1[c];
                    a00 = fma(x0, y0, a00);
                    a01 = fma(x0, y1, a01);
                    a10 = fma(x1, y0, a10);
                    a11 = fma(x1, y1, a11);
                }
            }
            if (half == 0) {
                h00 = a00; h01 = a01; h10 = a10; h11 = a11;
            } else {
                a00 = h00 + a00; a01 = h01 + a01;   // h0 + h1, as round 3
                a10 = h10 + a10; a11 = h11 + a11;
                simS[i0][j0] = a00; simS[j0][i0] = a00;
                simS[i0][j1] = a01; simS[j1][i0] = a01;
                simS[i1][j0] = a10; simS[j0][i1] = a10;
                simS[i1][j1] = a11; simS[j1][i1] = a11;
            }
        }
        // ---- qdot: lane (qm, qs) handles s = qs + 4*half, chain ascending d ----
        if (isQdot) {
            double acc = 0.0;
            const float* xr = &XtS[PR(qm)][0];
            const int kb = qs * 16;
            for (int k = kb; k < kb + 16; ++k) {
                float4 q4 = *(const float4*)(&QS[(half * 64 + k) << 2]);
                float4 x4 = *(const float4*)(xr + (k << 2));
                const float* qq = (const float*)&q4;
                const float* xx = (const float*)&x4;
                #pragma unroll
                for (int c = 0; c < 4; ++c)
                    acc = fma((double)qq[c], (double)xx[c], acc);
            }
            qdotPart[qm][qs + 4 * half] = acc;
        }
        __syncthreads();
    }

    // ---- wave-0 serial: qdot sum, top-20 selection, score, rank, head outputs ----
    const size_t sec = (size_t)B * MT;
    if (tid < MT) {
        {
            double acc = 0.0;
            #pragma unroll
            for (int s = 0; s < 8; ++s) acc += qdotPart[tid][s];
            qdotS[tid] = acc;
        }
        const int m = tid;
        unsigned used = 0;
        double Wsum = 0.0, sAcc = 0.0;
        for (int k = 0; k < KNB; ++k) {
            double best = -1.0e300; int bj = 0;
            for (int j = 0; j < MT; ++j) {
                if (used & (1u << j)) continue;
                double v = simS[m][j];
                if (v > best) { best = v; bj = j; }
            }
            used |= (1u << bj);
            double w = (k == 0) ? 1.0 : best * 0.15;
            Wsum += w;
            sAcc = fma(w, qdotS[bj], sAcc);
            MwS[m][bj] = (float)w;
        }
        scoreS[m] = sAcc / Wsum;
        float inv = (float)(1.0 / Wsum);
        for (int j = 0; j < MT; ++j)
            if (used & (1u << j)) MwS[m][j] *= inv;
        // stable rank (desc, ties -> lowest index)
        double mysc = scoreS[tid];
        int pos = 0;
        for (int j = 0; j < MT; ++j) {
            double v = scoreS[j];
            if (v > mysc || (v == mysc && j < tid)) ++pos;
        }
        orderS[pos] = tid;
        // head outputs
        int r = tid;
        int src = orderS[r];
        out[(size_t)b * MT + r]            = (float)rtS[src];
        out[sec + (size_t)b * MT + tid]    = (float)scoreS[tid];
        out[2 * sec + (size_t)b * MT + r]  = (float)src;
    }
    __syncthreads();

    // ---- export normalized weight matrix to workspace ----
    for (int i = tid; i < MT * MT; i += 256)
        wsF[(size_t)b * WSTRIDE + i] = (&MwS[0][0])[i];
}

// ===== Kernel B: x_dba = w(30x30) * gathered-X(30x512), register accumulators =====
extern "C" __global__ void __launch_bounds__(256)
mdesc_xdba(const float* __restrict__ X, const int* __restrict__ ranks,
           const float* __restrict__ wsF, float* __restrict__ out, int B)
{
    __shared__ float wS[MT][MT];
    __shared__ int   rtS[MT];

    const int b = blockIdx.x;
    const int tid = threadIdx.x;

    if (tid < MT) rtS[tid] = ranks[(size_t)tid * B + b];
    for (int i = tid; i < MT * MT; i += 256)
        (&wS[0][0])[i] = wsF[(size_t)b * WSTRIDE + i];
    __syncthreads();

    const int c  = tid & 127;          // float4 chunk 0..127
    const int g  = tid >> 7;           // row group 0 or 1 (15 rows each)
    const int r0 = g * 15;

    float4 acc[15];
    #pragma unroll
    for (int r = 0; r < 15; ++r) acc[r] = make_float4(0.f, 0.f, 0.f, 0.f);

    for (int j = 0; j < MT; ++j) {
        float4 xv = *(const float4*)(X + (size_t)rtS[j] * DD + (c << 2));
        #pragma unroll
        for (int r = 0; r < 15; ++r) {
            float wj = wS[r0 + r][j];
            acc[r].x = fmaf(wj, xv.x, acc[r].x);
            acc[r].y = fmaf(wj, xv.y, acc[r].y);
            acc[r].z = fmaf(wj, xv.z, acc[r].z);
            acc[r].w = fmaf(wj, xv.w, acc[r].w);
        }
    }

    const size_t xbase = 3 * (size_t)B * MT;
    #pragma unroll
    for (int r = 0; r < 15; ++r) {
        *(float4*)(out + xbase + ((size_t)b * MT + (r0 + r)) * DD + (c << 2)) = acc[r];
    }
}

extern "C" void kernel_launch(void* const* d_in, const int* in_sizes, int n_in,
                              void* d_out, int out_size, void* d_ws, size_t ws_size,
                              hipStream_t stream)
{
    const float* X = (const float*)d_in[0];
    const float* Q = (const float*)d_in[1];
    const int* ranks = (const int*)d_in[2];
    const int B = in_sizes[1] / DD;   // 4096
    float* wsF = (float*)d_ws;        // B*960 floats = 14.7 MB
    mdesc_decide<<<dim3(B), dim3(256), 0, stream>>>(X, Q, ranks, (float*)d_out, wsF, B);
    mdesc_xdba<<<dim3(B), dim3(256), 0, stream>>>(X, ranks, wsF, (float*)d_out, B);
}

// Round 9
// 295.988 us; speedup vs baseline: 3.3064x; 1.3011x over previous
//
#include <hip/hip_runtime.h>
#include <stdint.h>

#define MT   30      // top-M candidates
#define KNB  20      // K+1 neighbors
#define DD   512     // descriptor dim
#define SROW 68      // staged row stride (floats): 272B, 16B-aligned; with PR -> <=2-way banks
#define WSTRIDE 960  // per-query float stride of weight matrix in ws

// physical row permutation: even logical rows -> 0..14, odd -> 15..29
#define PR(r) ((((r) & 1) * 15) + ((r) >> 1))

// ===== Kernel A: decisions. Round-3 arithmetic chains verbatim; eighth-staged. =====
extern "C" __global__ void __launch_bounds__(256, 6)
mdesc_decide(const float* __restrict__ X, const float* __restrict__ Q,
             const int* __restrict__ ranks, float* __restrict__ out,
             float* __restrict__ wsF, int B)
{
    // XtS (stage phase) aliased with {MwS, scoreS, orderS} (post-stage phase)
    __shared__ alignas(16) char arrA[MT * SROW * 4];   // 8160 B
    __shared__ alignas(16) float QS[DD];
    __shared__ double simS[MT][MT + 1];
    __shared__ double qdotPart[MT][8];
    __shared__ double qdotS[MT];
    __shared__ int    rtS[MT];

    float  (*XtS)[SROW] = (float(*)[SROW])arrA;
    float  (*MwS)[MT]   = (float(*)[MT])arrA;          // 3600 B, after stages
    double *scoreS      = (double*)(arrA + 3600);      // 240 B
    int    *orderS      = (int*)(arrA + 3840);         // 120 B

    const int b = blockIdx.x;
    const int tid = threadIdx.x;

    if (tid < MT) rtS[tid] = ranks[(size_t)tid * B + b];
    __syncthreads();

    // roles: waves 0-1 = sim tiles (120 lanes), waves 2-3 = qdot (120 lanes)
    const bool isSim = (tid < 120);
    const bool isQ   = (tid >= 128 && tid < 248);
    int i0 = 0, i1 = 0, j0 = 0, j1 = 0;
    if (isSim) {
        int I = 0, rem = tid;
        while (rem >= 15 - I) { rem -= 15 - I; ++I; }
        int J = I + rem;
        i0 = 2 * I; i1 = i0 + 1; j0 = 2 * J; j1 = j0 + 1;
    }
    const int qm = (tid - 128) >> 2;   // 0..29
    const int qs = (tid - 128) & 3;    // 0..3

    double a00 = 0.0, a01 = 0.0, a10 = 0.0, a11 = 0.0;
    double h00 = 0.0, h01 = 0.0, h10 = 0.0, h11 = 0.0;

    for (int st = 0; st < 8; ++st) {
        // ---- stage 64 d-values of all 30 rows (coalesced float4) ----
        for (int i = tid; i < MT * 16; i += 256) {
            int row = i >> 4;
            int k = i & 15;
            float4 v = *(const float4*)(X + (size_t)rtS[row] * DD + st * 64 + (k << 2));
            *(float4*)(&XtS[PR(row)][k << 2]) = v;
        }
        if (st == 0 && tid < 128) {
            float4 v = *(const float4*)(Q + (size_t)b * DD + (tid << 2));
            *(float4*)(&QS[tid << 2]) = v;
        }
        __syncthreads();

        // ---- sim: continuous ascending-d f64 chains (verbatim round 3 per entry) ----
        if (isSim) {
            const float* R0 = &XtS[PR(i0)][0];
            const float* R1 = &XtS[PR(i1)][0];
            const float* C0 = &XtS[PR(j0)][0];
            const float* C1 = &XtS[PR(j1)][0];
            for (int k = 0; k < 16; ++k) {
                float4 va0 = *(const float4*)(R0 + (k << 2));
                float4 va1 = *(const float4*)(R1 + (k << 2));
                float4 vb0 = *(const float4*)(C0 + (k << 2));
                float4 vb1 = *(const float4*)(C1 + (k << 2));
                const float* A0 = (const float*)&va0;
                const float* A1 = (const float*)&va1;
                const float* B0 = (const float*)&vb0;
                const float* B1 = (const float*)&vb1;
                #pragma unroll
                for (int c = 0; c < 4; ++c) {
                    double x0 = (double)A0[c], x1 = (double)A1[c];
                    double y0 = (double)B0[c], y1 = (double)B1[c];
                    a00 = fma(x0, y0, a00);
                    a01 = fma(x0, y1, a01);
                    a10 = fma(x1, y0, a10);
                    a11 = fma(x1, y1, a11);
                }
            }
            if (st == 3) {              // end of half 0 (d 0..255)
                h00 = a00; h01 = a01; h10 = a10; h11 = a11;
                a00 = a01 = a10 = a11 = 0.0;
            }
            if (st == 7) {              // combine h0 + h1, as round 3
                double s00 = h00 + a00, s01 = h01 + a01;
                double s10 = h10 + a10, s11 = h11 + a11;
                simS[i0][j0] = s00; simS[j0][i0] = s00;
                simS[i0][j1] = s01; simS[j1][i0] = s01;
                simS[i1][j0] = s10; simS[j0][i1] = s10;
                simS[i1][j1] = s11; simS[j1][i1] = s11;
            }
        }
        // ---- qdot: lane (qm,qs) handles s = st when (st&3)==qs; 64-float chain ----
        if (isQ && (st & 3) == qs) {
            double acc = 0.0;
            const float* xr = &XtS[PR(qm)][0];
            for (int k = 0; k < 16; ++k) {
                float4 q4 = *(const float4*)(&QS[(st * 16 + k) << 2]);
                float4 x4 = *(const float4*)(xr + (k << 2));
                const float* qq = (const float*)&q4;
                const float* xx = (const float*)&x4;
                #pragma unroll
                for (int c = 0; c < 4; ++c)
                    acc = fma((double)qq[c], (double)xx[c], acc);
            }
            qdotPart[qm][st] = acc;
        }
        __syncthreads();
    }

    // ---- XtS dead; zero aliased MwS ----
    for (int i = tid; i < MT * MT; i += 256) (&MwS[0][0])[i] = 0.0f;
    __syncthreads();

    // ---- wave-0 serial: qdot sum, top-20 selection, score, rank, head outputs ----
    const size_t sec = (size_t)B * MT;
    if (tid < MT) {
        {
            double acc = 0.0;
            #pragma unroll
            for (int s = 0; s < 8; ++s) acc += qdotPart[tid][s];
            qdotS[tid] = acc;
        }
        const int m = tid;
        unsigned used = 0;
        double Wsum = 0.0, sAcc = 0.0;
        for (int k = 0; k < KNB; ++k) {
            double best = -1.0e300; int bj = 0;
            for (int j = 0; j < MT; ++j) {
                if (used & (1u << j)) continue;
                double v = simS[m][j];
                if (v > best) { best = v; bj = j; }
            }
            used |= (1u << bj);
            double w = (k == 0) ? 1.0 : best * 0.15;
            Wsum += w;
            sAcc = fma(w, qdotS[bj], sAcc);
            MwS[m][bj] = (float)w;
        }
        scoreS[m] = sAcc / Wsum;
        float inv = (float)(1.0 / Wsum);
        for (int j = 0; j < MT; ++j)
            if (used & (1u << j)) MwS[m][j] *= inv;
        // stable rank (desc, ties -> lowest index)
        double mysc = scoreS[tid];
        int pos = 0;
        for (int j = 0; j < MT; ++j) {
            double v = scoreS[j];
            if (v > mysc || (v == mysc && j < tid)) ++pos;
        }
        orderS[pos] = tid;
        // head outputs
        int r = tid;
        int src = orderS[r];
        out[(size_t)b * MT + r]            = (float)rtS[src];
        out[sec + (size_t)b * MT + tid]    = (float)scoreS[tid];
        out[2 * sec + (size_t)b * MT + r]  = (float)src;
    }
    __syncthreads();

    // ---- export normalized weight matrix to workspace ----
    for (int i = tid; i < MT * MT; i += 256)
        wsF[(size_t)b * WSTRIDE + i] = (&MwS[0][0])[i];
}

// ===== Kernel B: x_dba = w(30x30) * gathered-X(30x512), register accumulators =====
extern "C" __global__ void __launch_bounds__(256)
mdesc_xdba(const float* __restrict__ X, const int* __restrict__ ranks,
           const float* __restrict__ wsF, float* __restrict__ out, int B)
{
    __shared__ float wS[MT][MT];
    __shared__ int   rtS[MT];

    const int b = blockIdx.x;
    const int tid = threadIdx.x;

    if (tid < MT) rtS[tid] = ranks[(size_t)tid * B + b];
    for (int i = tid; i < MT * MT; i += 256)
        (&wS[0][0])[i] = wsF[(size_t)b * WSTRIDE + i];
    __syncthreads();

    const int c  = tid & 127;          // float4 chunk 0..127
    const int g  = tid >> 7;           // row group 0 or 1 (15 rows each)
    const int r0 = g * 15;

    float4 acc[15];
    #pragma unroll
    for (int r = 0; r < 15; ++r) acc[r] = make_float4(0.f, 0.f, 0.f, 0.f);

    for (int j = 0; j < MT; ++j) {
        float4 xv = *(const float4*)(X + (size_t)rtS[j] * DD + (c << 2));
        #pragma unroll
        for (int r = 0; r < 15; ++r) {
            float wj = wS[r0 + r][j];
            acc[r].x = fmaf(wj, xv.x, acc[r].x);
            acc[r].y = fmaf(wj, xv.y, acc[r].y);
            acc[r].z = fmaf(wj, xv.z, acc[r].z);
            acc[r].w = fmaf(wj, xv.w, acc[r].w);
        }
    }

    const size_t xbase = 3 * (size_t)B * MT;
    #pragma unroll
    for (int r = 0; r < 15; ++r) {
        *(float4*)(out + xbase + ((size_t)b * MT + (r0 + r)) * DD + (c << 2)) = acc[r];
    }
}

extern "C" void kernel_launch(void* const* d_in, const int* in_sizes, int n_in,
                              void* d_out, int out_size, void* d_ws, size_t ws_size,
                              hipStream_t stream)
{
    const float* X = (const float*)d_in[0];
    const float* Q = (const float*)d_in[1];
    const int* ranks = (const int*)d_in[2];
    const int B = in_sizes[1] / DD;   // 4096
    float* wsF = (float*)d_ws;        // B*960 floats = 14.7 MB
    mdesc_decide<<<dim3(B), dim3(256), 0, stream>>>(X, Q, ranks, (float*)d_out, wsF, B);
    mdesc_xdba<<<dim3(B), dim3(256), 0, stream>>>(X, ranks, wsF, (float*)d_out, B);
}

// Round 10
// 274.954 us; speedup vs baseline: 3.5594x; 1.0765x over previous
//
#include <hip/hip_runtime.h>
#include <stdint.h>

#define MT   30      // top-M candidates
#define KNB  20      // K+1 neighbors
#define DD   512     // descriptor dim
#define SROW 68      // staged row stride (floats): 272B, 16B-aligned
#define WSTRIDE 960  // per-query float stride of weight matrix in ws

// physical row permutation: even logical rows -> 0..14, odd -> 15..29
#define PR(r) ((((r) & 1) * 15) + ((r) >> 1))

// ===== Kernel A: decisions. Round-3 arithmetic chains verbatim; eighth-staged;
// ===== 8 blocks/CU: VGPR<=64 via h-accum stash in simS, LDS<=20KB. =====
extern "C" __global__ void __launch_bounds__(256, 8)
mdesc_decide(const float* __restrict__ X, const float* __restrict__ Q,
             const int* __restrict__ ranks, float* __restrict__ out,
             float* __restrict__ wsF, int B)
{
    // XtS (stage phase) aliased with {MwS, scoreS, orderS} (post-stage phase)
    __shared__ alignas(16) char arrA[MT * SROW * 4];   // 8160 B
    __shared__ alignas(16) float QS[DD];
    __shared__ double simS[MT][MT + 1];
    __shared__ double qdotPart[MT][8];
    __shared__ double qdotS[MT];
    __shared__ int    rtS[MT];

    float  (*XtS)[SROW] = (float(*)[SROW])arrA;
    float  (*MwS)[MT]   = (float(*)[MT])arrA;          // 3600 B, after stages
    double *scoreS      = (double*)(arrA + 3600);      // 240 B
    int    *orderS      = (int*)(arrA + 3840);         // 120 B

    const int b = blockIdx.x;
    const int tid = threadIdx.x;

    if (tid < MT) rtS[tid] = ranks[(size_t)tid * B + b];
    __syncthreads();

    // roles: waves 0-1 = sim tiles (120 lanes), waves 2-3 = qdot (120 lanes)
    const bool isSim = (tid < 120);
    const bool isQ   = (tid >= 128 && tid < 248);
    int i0 = 0, i1 = 0, j0 = 0, j1 = 0;
    if (isSim) {
        int I = 0, rem = tid;
        while (rem >= 15 - I) { rem -= 15 - I; ++I; }
        int J = I + rem;
        i0 = 2 * I; i1 = i0 + 1; j0 = 2 * J; j1 = j0 + 1;
    }
    const int qm = (tid - 128) >> 2;   // 0..29
    const int qs = (tid - 128) & 3;    // 0..3

    double a00 = 0.0, a01 = 0.0, a10 = 0.0, a11 = 0.0;

    for (int st = 0; st < 8; ++st) {
        // ---- stage 64 d-values of all 30 rows (coalesced float4) ----
        for (int i = tid; i < MT * 16; i += 256) {
            int row = i >> 4;
            int k = i & 15;
            float4 v = *(const float4*)(X + (size_t)rtS[row] * DD + st * 64 + (k << 2));
            *(float4*)(&XtS[PR(row)][k << 2]) = v;
        }
        if (st == 0 && tid < 128) {
            float4 v = *(const float4*)(Q + (size_t)b * DD + (tid << 2));
            *(float4*)(&QS[tid << 2]) = v;
        }
        __syncthreads();

        // ---- sim: continuous ascending-d f64 chains (verbatim round 3 per entry) ----
        if (isSim) {
            const float* R0 = &XtS[PR(i0)][0];
            const float* R1 = &XtS[PR(i1)][0];
            const float* C0 = &XtS[PR(j0)][0];
            const float* C1 = &XtS[PR(j1)][0];
            for (int k = 0; k < 16; ++k) {
                float4 va0 = *(const float4*)(R0 + (k << 2));
                float4 va1 = *(const float4*)(R1 + (k << 2));
                float4 vb0 = *(const float4*)(C0 + (k << 2));
                float4 vb1 = *(const float4*)(C1 + (k << 2));
                const float* A0 = (const float*)&va0;
                const float* A1 = (const float*)&va1;
                const float* B0 = (const float*)&vb0;
                const float* B1 = (const float*)&vb1;
                #pragma unroll
                for (int c = 0; c < 4; ++c) {
                    double x0 = (double)A0[c], x1 = (double)A1[c];
                    double y0 = (double)B0[c], y1 = (double)B1[c];
                    a00 = fma(x0, y0, a00);
                    a01 = fma(x0, y1, a01);
                    a10 = fma(x1, y0, a10);
                    a11 = fma(x1, y1, a11);
                }
            }
            if (st == 3) {              // end of half 0: stash in own simS slots
                simS[i0][j0] = a00; simS[i0][j1] = a01;
                simS[i1][j0] = a10; simS[i1][j1] = a11;
                a00 = a01 = a10 = a11 = 0.0;
            }
            if (st == 7) {              // combine h0 + h1, exactly as round 3
                double s00 = simS[i0][j0] + a00;
                double s01 = simS[i0][j1] + a01;
                double s10 = simS[i1][j0] + a10;
                double s11 = simS[i1][j1] + a11;
                simS[i0][j0] = s00; simS[j0][i0] = s00;
                simS[i0][j1] = s01; simS[j1][i0] = s01;
                simS[i1][j0] = s10; simS[j0][i1] = s10;
                simS[i1][j1] = s11; simS[j1][i1] = s11;
            }
        }
        // ---- qdot: lane (qm,qs) handles s = st when (st&3)==qs; 64-float chain ----
        if (isQ && (st & 3) == qs) {
            double acc = 0.0;
            const float* xr = &XtS[PR(qm)][0];
            for (int k = 0; k < 16; ++k) {
                float4 q4 = *(const float4*)(&QS[(st * 16 + k) << 2]);
                float4 x4 = *(const float4*)(xr + (k << 2));
                const float* qq = (const float*)&q4;
                const float* xx = (const float*)&x4;
                #pragma unroll
                for (int c = 0; c < 4; ++c)
                    acc = fma((double)qq[c], (double)xx[c], acc);
            }
            qdotPart[qm][st] = acc;
        }
        __syncthreads();
    }

    // ---- XtS dead; zero aliased MwS ----
    for (int i = tid; i < MT * MT; i += 256) (&MwS[0][0])[i] = 0.0f;
    __syncthreads();

    // ---- wave-0 serial: qdot sum, top-20 selection, score, rank, head outputs ----
    const size_t sec = (size_t)B * MT;
    if (tid < MT) {
        {
            double acc = 0.0;
            #pragma unroll
            for (int s = 0; s < 8; ++s) acc += qdotPart[tid][s];
            qdotS[tid] = acc;
        }
        const int m = tid;
        unsigned used = 0;
        double Wsum = 0.0, sAcc = 0.0;
        for (int k = 0; k < KNB; ++k) {
            double best = -1.0e300; int bj = 0;
            for (int j = 0; j < MT; ++j) {
                if (used & (1u << j)) continue;
                double v = simS[m][j];
                if (v > best) { best = v; bj = j; }
            }
            used |= (1u << bj);
            double w = (k == 0) ? 1.0 : best * 0.15;
            Wsum += w;
            sAcc = fma(w, qdotS[bj], sAcc);
            MwS[m][bj] = (float)w;
        }
        scoreS[m] = sAcc / Wsum;
        float inv = (float)(1.0 / Wsum);
        for (int j = 0; j < MT; ++j)
            if (used & (1u << j)) MwS[m][j] *= inv;
        // stable rank (desc, ties -> lowest index)
        double mysc = scoreS[tid];
        int pos = 0;
        for (int j = 0; j < MT; ++j) {
            double v = scoreS[j];
            if (v > mysc || (v == mysc && j < tid)) ++pos;
        }
        orderS[pos] = tid;
        // head outputs
        int r = tid;
        int src = orderS[r];
        out[(size_t)b * MT + r]            = (float)rtS[src];
        out[sec + (size_t)b * MT + tid]    = (float)scoreS[tid];
        out[2 * sec + (size_t)b * MT + r]  = (float)src;
    }
    __syncthreads();

    // ---- export normalized weight matrix to workspace ----
    for (int i = tid; i < MT * MT; i += 256)
        wsF[(size_t)b * WSTRIDE + i] = (&MwS[0][0])[i];
}

// ===== Kernel B: x_dba = w(30x30) * gathered-X(30x512), register accumulators =====
extern "C" __global__ void __launch_bounds__(256)
mdesc_xdba(const float* __restrict__ X, const int* __restrict__ ranks,
           const float* __restrict__ wsF, float* __restrict__ out, int B)
{
    __shared__ float wS[MT][MT];
    __shared__ int   rtS[MT];

    const int b = blockIdx.x;
    const int tid = threadIdx.x;

    if (tid < MT) rtS[tid] = ranks[(size_t)tid * B + b];
    for (int i = tid; i < MT * MT; i += 256)
        (&wS[0][0])[i] = wsF[(size_t)b * WSTRIDE + i];
    __syncthreads();

    const int c  = tid & 127;          // float4 chunk 0..127
    const int g  = tid >> 7;           // row group 0 or 1 (15 rows each)
    const int r0 = g * 15;

    float4 acc[15];
    #pragma unroll
    for (int r = 0; r < 15; ++r) acc[r] = make_float4(0.f, 0.f, 0.f, 0.f);

    for (int j = 0; j < MT; ++j) {
        float4 xv = *(const float4*)(X + (size_t)rtS[j] * DD + (c << 2));
        #pragma unroll
        for (int r = 0; r < 15; ++r) {
            float wj = wS[r0 + r][j];
            acc[r].x = fmaf(wj, xv.x, acc[r].x);
            acc[r].y = fmaf(wj, xv.y, acc[r].y);
            acc[r].z = fmaf(wj, xv.z, acc[r].z);
            acc[r].w = fmaf(wj, xv.w, acc[r].w);
        }
    }

    const size_t xbase = 3 * (size_t)B * MT;
    #pragma unroll
    for (int r = 0; r < 15; ++r) {
        *(float4*)(out + xbase + ((size_t)b * MT + (r0 + r)) * DD + (c << 2)) = acc[r];
    }
}

extern "C" void kernel_launch(void* const* d_in, const int* in_sizes, int n_in,
                              void* d_out, int out_size, void* d_ws, size_t ws_size,
                              hipStream_t stream)
{
    const float* X = (const float*)d_in[0];
    const float* Q = (const float*)d_in[1];
    const int* ranks = (const int*)d_in[2];
    const int B = in_sizes[1] / DD;   // 4096
    float* wsF = (float*)d_ws;        // B*960 floats = 14.7 MB
    mdesc_decide<<<dim3(B), dim3(256), 0, stream>>>(X, Q, ranks, (float*)d_out, wsF, B);
    mdesc_xdba<<<dim3(B), dim3(256), 0, stream>>>(X, ranks, wsF, (float*)d_out, B);
}

// Round 11
// 245.145 us; speedup vs baseline: 3.9922x; 1.1216x over previous
//
#include <hip/hip_runtime.h>
#include <stdint.h>

#define MT   30      // top-M candidates
#define KNB  20      // K+1 neighbors
#define DD   512     // descriptor dim
#define SROW 68      // staged row stride (floats): 272B, 16B-aligned
#define MWS  32      // padded MwS row stride (floats): 128B, 16B-aligned

// physical row permutation: even logical rows -> 0..14, odd -> 15..29
#define PR(r) ((((r) & 1) * 15) + ((r) >> 1))

// ===== Fused kernel: decisions (round-3 chains verbatim) + x_dba tail =====
extern "C" __global__ void __launch_bounds__(256, 6)
mdesc_fused(const float* __restrict__ X, const float* __restrict__ Q,
            const int* __restrict__ ranks, float* __restrict__ out, int B)
{
    // arrA: XtS (stage phase) aliased with {MwS, scoreS, orderS} (post-stage)
    __shared__ alignas(16) char arrA[MT * SROW * 4];   // 8160 B
    __shared__ alignas(16) float QS[DD];
    __shared__ double simS[MT][MT + 1];
    __shared__ double qdotPart[MT][8];
    __shared__ double qdotS[MT];
    __shared__ int    rtS[MT];

    float  (*XtS)[SROW] = (float(*)[SROW])arrA;
    float  (*MwS)[MWS]  = (float(*)[MWS])arrA;         // 30x32 f32 = 3840 B
    double *scoreS      = (double*)(arrA + 3840);      // 240 B
    int    *orderS      = (int*)(arrA + 4080);         // 120 B

    const int b = blockIdx.x;
    const int tid = threadIdx.x;

    if (tid < MT) rtS[tid] = ranks[(size_t)tid * B + b];
    __syncthreads();

    // roles: waves 0-1 = sim tiles (120 lanes), waves 2-3 = qdot (120 lanes)
    const bool isSim = (tid < 120);
    const bool isQ   = (tid >= 128 && tid < 248);
    int i0 = 0, i1 = 0, j0 = 0, j1 = 0;
    if (isSim) {
        int I = 0, rem = tid;
        while (rem >= 15 - I) { rem -= 15 - I; ++I; }
        int J = I + rem;
        i0 = 2 * I; i1 = i0 + 1; j0 = 2 * J; j1 = j0 + 1;
    }
    const int qm = (tid - 128) >> 2;   // 0..29
    const int qs = (tid - 128) & 3;    // 0..3

    double a00 = 0.0, a01 = 0.0, a10 = 0.0, a11 = 0.0;

    for (int st = 0; st < 8; ++st) {
        // ---- stage 64 d-values of all 30 rows (coalesced float4) ----
        for (int i = tid; i < MT * 16; i += 256) {
            int row = i >> 4;
            int k = i & 15;
            float4 v = *(const float4*)(X + (size_t)rtS[row] * DD + st * 64 + (k << 2));
            *(float4*)(&XtS[PR(row)][k << 2]) = v;
        }
        if (st == 0 && tid < 128) {
            float4 v = *(const float4*)(Q + (size_t)b * DD + (tid << 2));
            *(float4*)(&QS[tid << 2]) = v;
        }
        __syncthreads();

        // ---- sim: continuous ascending-d f64 chains (verbatim round 3 per entry) ----
        if (isSim) {
            const float* R0 = &XtS[PR(i0)][0];
            const float* R1 = &XtS[PR(i1)][0];
            const float* C0 = &XtS[PR(j0)][0];
            const float* C1 = &XtS[PR(j1)][0];
            for (int k = 0; k < 16; ++k) {
                float4 va0 = *(const float4*)(R0 + (k << 2));
                float4 va1 = *(const float4*)(R1 + (k << 2));
                float4 vb0 = *(const float4*)(C0 + (k << 2));
                float4 vb1 = *(const float4*)(C1 + (k << 2));
                const float* A0 = (const float*)&va0;
                const float* A1 = (const float*)&va1;
                const float* B0 = (const float*)&vb0;
                const float* B1 = (const float*)&vb1;
                #pragma unroll
                for (int c = 0; c < 4; ++c) {
                    double x0 = (double)A0[c], x1 = (double)A1[c];
                    double y0 = (double)B0[c], y1 = (double)B1[c];
                    a00 = fma(x0, y0, a00);
                    a01 = fma(x0, y1, a01);
                    a10 = fma(x1, y0, a10);
                    a11 = fma(x1, y1, a11);
                }
            }
            if (st == 3) {              // end of half 0: stash in own simS slots
                simS[i0][j0] = a00; simS[i0][j1] = a01;
                simS[i1][j0] = a10; simS[i1][j1] = a11;
                a00 = a01 = a10 = a11 = 0.0;
            }
            if (st == 7) {              // combine h0 + h1, exactly as round 3
                double s00 = simS[i0][j0] + a00;
                double s01 = simS[i0][j1] + a01;
                double s10 = simS[i1][j0] + a10;
                double s11 = simS[i1][j1] + a11;
                simS[i0][j0] = s00; simS[j0][i0] = s00;
                simS[i0][j1] = s01; simS[j1][i0] = s01;
                simS[i1][j0] = s10; simS[j0][i1] = s10;
                simS[i1][j1] = s11; simS[j1][i1] = s11;
            }
        }
        // ---- qdot: lane (qm,qs) handles s = st when (st&3)==qs; 64-float chain ----
        if (isQ && (st & 3) == qs) {
            double acc = 0.0;
            const float* xr = &XtS[PR(qm)][0];
            for (int k = 0; k < 16; ++k) {
                float4 q4 = *(const float4*)(&QS[(st * 16 + k) << 2]);
                float4 x4 = *(const float4*)(xr + (k << 2));
                const float* qq = (const float*)&q4;
                const float* xx = (const float*)&x4;
                #pragma unroll
                for (int c = 0; c < 4; ++c)
                    acc = fma((double)qq[c], (double)xx[c], acc);
            }
            qdotPart[qm][st] = acc;
        }
        __syncthreads();
    }

    // ---- XtS dead; zero aliased MwS (padded 30x32) ----
    for (int i = tid; i < MT * MWS; i += 256) (&MwS[0][0])[i] = 0.0f;
    __syncthreads();

    // ---- wave-0 serial: qdot sum, top-20 selection, score, rank, head outputs ----
    const size_t sec = (size_t)B * MT;
    if (tid < MT) {
        {
            double acc = 0.0;
            #pragma unroll
            for (int s = 0; s < 8; ++s) acc += qdotPart[tid][s];
            qdotS[tid] = acc;
        }
        const int m = tid;
        unsigned used = 0;
        double Wsum = 0.0, sAcc = 0.0;
        for (int k = 0; k < KNB; ++k) {
            double best = -1.0e300; int bj = 0;
            for (int j = 0; j < MT; ++j) {
                if (used & (1u << j)) continue;
                double v = simS[m][j];
                if (v > best) { best = v; bj = j; }
            }
            used |= (1u << bj);
            double w = (k == 0) ? 1.0 : best * 0.15;
            Wsum += w;
            sAcc = fma(w, qdotS[bj], sAcc);
            MwS[m][bj] = (float)w;
        }
        scoreS[m] = sAcc / Wsum;
        float inv = (float)(1.0 / Wsum);
        for (int j = 0; j < MT; ++j)
            if (used & (1u << j)) MwS[m][j] *= inv;
        // stable rank (desc, ties -> lowest index)
        double mysc = scoreS[tid];
        int pos = 0;
        for (int j = 0; j < MT; ++j) {
            double v = scoreS[j];
            if (v > mysc || (v == mysc && j < tid)) ++pos;
        }
        orderS[pos] = tid;
        // head outputs
        int r = tid;
        int src = orderS[r];
        out[(size_t)b * MT + r]            = (float)rtS[src];
        out[sec + (size_t)b * MT + tid]    = (float)scoreS[tid];
        out[2 * sec + (size_t)b * MT + r]  = (float)src;
    }
    __syncthreads();

    // ---- fused x_dba tail: X from global (L2-hot), w as b64 broadcasts ----
    {
        const int sub = tid >> 7;          // 0..1 (15-row group)
        const int c   = tid & 127;         // float4 chunk
        const int r0  = sub * 15;
        float4 acc[15];
        #pragma unroll
        for (int r = 0; r < 15; ++r) acc[r] = make_float4(0.f, 0.f, 0.f, 0.f);

        for (int jg = 0; jg < 15; ++jg) {
            const int ja = 2 * jg, jb = ja + 1;
            float4 xv0 = *(const float4*)(X + (size_t)rtS[ja] * DD + (c << 2));
            float4 xv1 = *(const float4*)(X + (size_t)rtS[jb] * DD + (c << 2));
            #pragma unroll
            for (int r = 0; r < 15; ++r) {
                float2 wv = *(const float2*)&MwS[r0 + r][ja];   // 8B-aligned broadcast
                acc[r].x = fmaf(wv.x, xv0.x, acc[r].x);
                acc[r].x = fmaf(wv.y, xv1.x, acc[r].x);
                acc[r].y = fmaf(wv.x, xv0.y, acc[r].y);
                acc[r].y = fmaf(wv.y, xv1.y, acc[r].y);
                acc[r].z = fmaf(wv.x, xv0.z, acc[r].z);
                acc[r].z = fmaf(wv.y, xv1.z, acc[r].z);
                acc[r].w = fmaf(wv.x, xv0.w, acc[r].w);
                acc[r].w = fmaf(wv.y, xv1.w, acc[r].w);
            }
        }

        const size_t xbase = 3 * sec;
        #pragma unroll
        for (int r = 0; r < 15; ++r) {
            *(float4*)(out + xbase + ((size_t)b * MT + (r0 + r)) * DD + (c << 2)) = acc[r];
        }
    }
}

extern "C" void kernel_launch(void* const* d_in, const int* in_sizes, int n_in,
                              void* d_out, int out_size, void* d_ws, size_t ws_size,
                              hipStream_t stream)
{
    const float* X = (const float*)d_in[0];
    const float* Q = (const float*)d_in[1];
    const int* ranks = (const int*)d_in[2];
    const int B = in_sizes[1] / DD;   // 4096
    mdesc_fused<<<dim3(B), dim3(256), 0, stream>>>(X, Q, ranks, (float*)d_out, B);
}